// Round 7
// baseline (179.492 us; speedup 1.0000x reference)
//
#include <hip/hip_runtime.h>
#include <math.h>

// Problem sizes (fixed by the reference)
#define B   4
#define TQ  256
#define TV  1024
#define D   512
#define A   128

#define LOG2E     1.4426950408889634f
#define TWO_LOG2E 2.8853900817779268f
#define NEG_BIG_F (-1e9f)

#define QBLK (B * TQ / 8)   // 128 q-projection blocks
#define KBLK (B * TV / 8)   // 512 k-projection blocks

// ---------------------------------------------------------------------------
// Fused projection + exp(2x) for BOTH q and k.
//   q path: Eq[r, a]     = exp(2*(ctx[r,:]@Wq[:,a] + bq[a]))   [row-major]
//   k path: EkT[b, a, v] = exp(2*(inp[r,:]@Wk[:,a] + bk[a]))   [TRANSPOSED]
// X values are read with WAVE-UNIFORM addresses -> compiler emits scalar
// s_load_dwordx4 (SGPR operand into v_fma). No LDS staging: frees the LDS
// pipe, which was the round-6 bottleneck (8 ds_read_b128 per 32 FMA-cyc).
// ---------------------------------------------------------------------------
__global__ __launch_bounds__(512, 4) void proj_exp_kernel(
    const float* __restrict__ ctx, const float* __restrict__ inp,
    const float* __restrict__ Wq, const float* __restrict__ bq,
    const float* __restrict__ Wk, const float* __restrict__ bk,
    float* __restrict__ Eq, float* __restrict__ EkT) {
  __shared__ float ps[8][4][A];     // 16 KB (row j, quarter, a)
  __shared__ float es[A][9];        // 4.6 KB (transpose staging, +1 pad)

  bool isQ = blockIdx.x < QBLK;
  const float* X; const float* W; const float* bias; int r0;
  if (isQ) { X = ctx; W = Wq; bias = bq; r0 = blockIdx.x * 8; }
  else     { X = inp; W = Wk; bias = bk; r0 = (blockIdx.x - QBLK) * 8; }

  int a = threadIdx.x & 127;
  int h = threadIdx.x >> 7;        // 0..3, splits d-range into quarters
  float acc[8];
#pragma unroll
  for (int j = 0; j < 8; ++j) acc[j] = 0.f;

  const float* Xr = X + (size_t)r0 * D;   // wave-uniform base
  int dbase = h * (D / 4);
#pragma unroll 2
  for (int dd = 0; dd < D / 4; dd += 4) {
    int d = dbase + dd;
    float w0 = W[(d + 0) * A + a];
    float w1 = W[(d + 1) * A + a];
    float w2 = W[(d + 2) * A + a];
    float w3 = W[(d + 3) * A + a];
#pragma unroll
    for (int j = 0; j < 8; ++j) {
      // wave-uniform address -> scalar load (SGPR), no LDS, no per-lane VMEM
      float4 x = *(const float4*)(Xr + (size_t)j * D + d);
      acc[j] = fmaf(x.x, w0, acc[j]);
      acc[j] = fmaf(x.y, w1, acc[j]);
      acc[j] = fmaf(x.z, w2, acc[j]);
      acc[j] = fmaf(x.w, w3, acc[j]);
    }
  }
#pragma unroll
  for (int j = 0; j < 8; ++j) ps[j][h][a] = acc[j];
  __syncthreads();

  float bz = bias[a];
  if (isQ) {
#pragma unroll
    for (int j = h * 2; j < h * 2 + 2; ++j) {
      float t = ((ps[j][0][a] + ps[j][1][a]) + (ps[j][2][a] + ps[j][3][a])) + bz;
      Eq[(size_t)(r0 + j) * A + a] = __builtin_amdgcn_exp2f(t * TWO_LOG2E);
    }
  } else {
#pragma unroll
    for (int j = h * 2; j < h * 2 + 2; ++j) {
      float t = ((ps[j][0][a] + ps[j][1][a]) + (ps[j][2][a] + ps[j][3][a])) + bz;
      es[a][j] = __builtin_amdgcn_exp2f(t * TWO_LOG2E);
    }
    __syncthreads();
    int b  = r0 >> 10;          // TV == 1024
    int v0 = r0 & (TV - 1);
    for (int i = threadIdx.x; i < A * 8; i += 512) {
      int aa = i >> 3, jj = i & 7;
      EkT[((size_t)b * A + aa) * TV + v0 + jj] = es[aa][jj];
    }
  }
}

// ---------------------------------------------------------------------------
// Scores + softmax: TWO q rows per block, 256 threads (4 waves), 512 blocks
// -> 2 blocks/CU, 8 waves/CU. Thread owns 4 consecutive v for both rows
// (8 independent rcp chains per EkT float4 load). Prefetch distance 2 covers
// the ~250-cyc L2 latency.
//   score[v] = sumV - 2 * sum_a v_a / (Eq[a]*EkT[a,v] + 1)
// ---------------------------------------------------------------------------
__global__ __launch_bounds__(256, 4) void score_softmax_kernel(
    const float* __restrict__ Eq, const float* __restrict__ EkT,
    const float* __restrict__ attn_v, const int* __restrict__ mask,
    float* __restrict__ attn) {
  __shared__ float redA[4], redB[4];
  __shared__ float bc[4];

  int tid = threadIdx.x;
  int v0  = (tid & 63) * 4 + (tid >> 6) * 256;  // wave-contiguous float4
  int r0  = blockIdx.x * 2;
  int b   = r0 >> 8;               // TQ == 256

  const float* eqA = Eq + (size_t)r0 * A;
  const float* eqB = eqA + A;

  float sumV = 0.f;
#pragma unroll 16
  for (int i = 0; i < A; ++i) sumV += attn_v[i];

  const float* ekb = EkT + (size_t)b * A * TV + v0;
  float4 tA = make_float4(0.f, 0.f, 0.f, 0.f);
  float4 tB = make_float4(0.f, 0.f, 0.f, 0.f);

  float4 e0 = *(const float4*)(ekb);
  float4 e1 = *(const float4*)(ekb + (size_t)TV);
#pragma unroll 4
  for (int i = 0; i < A; ++i) {
    float4 en;
    if (i < A - 2) en = *(const float4*)(ekb + (size_t)(i + 2) * TV);
    float av = attn_v[i];
    float qa = eqA[i];
    float qb = eqB[i];
    tA.x = fmaf(av, __builtin_amdgcn_rcpf(fmaf(e0.x, qa, 1.f)), tA.x);
    tA.y = fmaf(av, __builtin_amdgcn_rcpf(fmaf(e0.y, qa, 1.f)), tA.y);
    tA.z = fmaf(av, __builtin_amdgcn_rcpf(fmaf(e0.z, qa, 1.f)), tA.z);
    tA.w = fmaf(av, __builtin_amdgcn_rcpf(fmaf(e0.w, qa, 1.f)), tA.w);
    tB.x = fmaf(av, __builtin_amdgcn_rcpf(fmaf(e0.x, qb, 1.f)), tB.x);
    tB.y = fmaf(av, __builtin_amdgcn_rcpf(fmaf(e0.y, qb, 1.f)), tB.y);
    tB.z = fmaf(av, __builtin_amdgcn_rcpf(fmaf(e0.z, qb, 1.f)), tB.z);
    tB.w = fmaf(av, __builtin_amdgcn_rcpf(fmaf(e0.w, qb, 1.f)), tB.w);
    e0 = e1;
    e1 = en;
  }

  int4 mk = *(const int4*)(mask + b * TV + v0);
  float4 sA, sB;
  sA.x = sumV - 2.f * tA.x + (1.f - (float)mk.x) * NEG_BIG_F;
  sA.y = sumV - 2.f * tA.y + (1.f - (float)mk.y) * NEG_BIG_F;
  sA.z = sumV - 2.f * tA.z + (1.f - (float)mk.z) * NEG_BIG_F;
  sA.w = sumV - 2.f * tA.w + (1.f - (float)mk.w) * NEG_BIG_F;
  sB.x = sumV - 2.f * tB.x + (1.f - (float)mk.x) * NEG_BIG_F;
  sB.y = sumV - 2.f * tB.y + (1.f - (float)mk.y) * NEG_BIG_F;
  sB.z = sumV - 2.f * tB.z + (1.f - (float)mk.z) * NEG_BIG_F;
  sB.w = sumV - 2.f * tB.w + (1.f - (float)mk.w) * NEG_BIG_F;

  float mA = fmaxf(fmaxf(sA.x, sA.y), fmaxf(sA.z, sA.w));
  float mB = fmaxf(fmaxf(sB.x, sB.y), fmaxf(sB.z, sB.w));
  for (int off = 32; off > 0; off >>= 1) {
    mA = fmaxf(mA, __shfl_down(mA, off, 64));
    mB = fmaxf(mB, __shfl_down(mB, off, 64));
  }
  int w = tid >> 6;
  if ((tid & 63) == 0) { redA[w] = mA; redB[w] = mB; }
  __syncthreads();
  if (tid == 0) {
    bc[0] = fmaxf(fmaxf(redA[0], redA[1]), fmaxf(redA[2], redA[3]));
    bc[1] = fmaxf(fmaxf(redB[0], redB[1]), fmaxf(redB[2], redB[3]));
  }
  __syncthreads();
  float MA = bc[0], MB = bc[1];

  float4 eAv, eBv;
  eAv.x = __builtin_amdgcn_exp2f((sA.x - MA) * LOG2E);
  eAv.y = __builtin_amdgcn_exp2f((sA.y - MA) * LOG2E);
  eAv.z = __builtin_amdgcn_exp2f((sA.z - MA) * LOG2E);
  eAv.w = __builtin_amdgcn_exp2f((sA.w - MA) * LOG2E);
  eBv.x = __builtin_amdgcn_exp2f((sB.x - MB) * LOG2E);
  eBv.y = __builtin_amdgcn_exp2f((sB.y - MB) * LOG2E);
  eBv.z = __builtin_amdgcn_exp2f((sB.z - MB) * LOG2E);
  eBv.w = __builtin_amdgcn_exp2f((sB.w - MB) * LOG2E);
  float lA = (eAv.x + eAv.y) + (eAv.z + eAv.w);
  float lB = (eBv.x + eBv.y) + (eBv.z + eBv.w);
  for (int off = 32; off > 0; off >>= 1) {
    lA += __shfl_down(lA, off, 64);
    lB += __shfl_down(lB, off, 64);
  }
  __syncthreads();   // protect red[] before rewrite
  if ((tid & 63) == 0) { redA[w] = lA; redB[w] = lB; }
  __syncthreads();
  if (tid == 0) {
    bc[2] = (redA[0] + redA[1]) + (redA[2] + redA[3]);
    bc[3] = (redB[0] + redB[1]) + (redB[2] + redB[3]);
  }
  __syncthreads();
  float iA = 1.f / bc[2];
  float iB = 1.f / bc[3];

  float4 oA = make_float4(eAv.x * iA, eAv.y * iA, eAv.z * iA, eAv.w * iA);
  float4 oB = make_float4(eBv.x * iB, eBv.y * iB, eBv.z * iB, eBv.w * iB);
  *(float4*)(attn + (size_t)r0 * TV + v0)       = oA;
  *(float4*)(attn + (size_t)(r0 + 1) * TV + v0) = oB;
}

// ---------------------------------------------------------------------------
// out[b,q,:] = sum_v attn[b,q,v] * inputs[b,v,:]   -- NO ATOMICS.
// Block tile: 8 q x 128 d over the FULL v range; v-sum split across the 8
// waves (disjoint 128-v chunks, no duplicated X traffic), wave partials
// reduced through LDS (reusing the 32 KB attn-tile buffer), plain coalesced
// store. grid (dt=4, qtile=128) = 512 blocks x 512 thr -> 2 blocks/CU,
// 16 waves/CU. Register tile 4q x 4d = 16 acc; 16 FMA per X float4 load.
// ---------------------------------------------------------------------------
__global__ __launch_bounds__(512, 4) void pv_kernel(
    const float* __restrict__ attn, const float* __restrict__ X,
    float* __restrict__ out) {
  __shared__ float lds[8 * 1024];    // 32 KB: attn tile, then 8 partial tiles
  int dt = blockIdx.x;               // 0..3, d-slice of 128
  int q0 = blockIdx.y * 8;           // global row (b*TQ + q), 128 tiles
  int b  = q0 >> 8;                  // TQ == 256
  int tid  = threadIdx.x;
  int w    = tid >> 6;               // wave 0..7 -> v range [w*128, w*128+128)
  int lane = tid & 63;
  int col  = lane & 31;              // float4 d-column
  int qh   = lane >> 5;              // 0..1 -> q rows qh*4 .. qh*4+3
  int d0 = dt * 128 + col * 4;

  // stage attn tile: 8 rows x 1024 v (float4, coalesced)
  {
    const float4* src = (const float4*)(attn + (size_t)q0 * TV);
    float4* dst = (float4*)lds;
    for (int i = tid; i < 8 * 256; i += 512) dst[i] = src[i];
  }
  __syncthreads();

  float4 acc[4];
#pragma unroll
  for (int j = 0; j < 4; ++j) acc[j] = make_float4(0.f, 0.f, 0.f, 0.f);

  int vbase = w * 128;
  const float* Xb = X + ((size_t)b * TV + vbase) * D + d0;
  const float* arow = &lds[(qh * 4) * 1024 + vbase];  // 4 rows, stride 1024

  float4 xc0 = *(const float4*)(Xb + (size_t)0 * D);
  float4 xc1 = *(const float4*)(Xb + (size_t)1 * D);
  float4 xc2 = *(const float4*)(Xb + (size_t)2 * D);
  float4 xc3 = *(const float4*)(Xb + (size_t)3 * D);

  for (int vi = 0; vi < 128; vi += 4) {
    float4 xn0, xn1, xn2, xn3;
    if (vi < 124) {
      const float* Xn = Xb + (size_t)(vi + 4) * D;
      xn0 = *(const float4*)(Xn + (size_t)0 * D);
      xn1 = *(const float4*)(Xn + (size_t)1 * D);
      xn2 = *(const float4*)(Xn + (size_t)2 * D);
      xn3 = *(const float4*)(Xn + (size_t)3 * D);
    }
#pragma unroll
    for (int j = 0; j < 4; ++j) {
      float4 av = *(const float4*)(arow + j * 1024 + vi);  // 2-addr bcast
      acc[j].x = fmaf(av.x, xc0.x, acc[j].x);
      acc[j].y = fmaf(av.x, xc0.y, acc[j].y);
      acc[j].z = fmaf(av.x, xc0.z, acc[j].z);
      acc[j].w = fmaf(av.x, xc0.w, acc[j].w);
      acc[j].x = fmaf(av.y, xc1.x, acc[j].x);
      acc[j].y = fmaf(av.y, xc1.y, acc[j].y);
      acc[j].z = fmaf(av.y, xc1.z, acc[j].z);
      acc[j].w = fmaf(av.y, xc1.w, acc[j].w);
      acc[j].x = fmaf(av.z, xc2.x, acc[j].x);
      acc[j].y = fmaf(av.z, xc2.y, acc[j].y);
      acc[j].z = fmaf(av.z, xc2.z, acc[j].z);
      acc[j].w = fmaf(av.z, xc2.w, acc[j].w);
      acc[j].x = fmaf(av.w, xc3.x, acc[j].x);
      acc[j].y = fmaf(av.w, xc3.y, acc[j].y);
      acc[j].z = fmaf(av.w, xc3.z, acc[j].z);
      acc[j].w = fmaf(av.w, xc3.w, acc[j].w);
    }
    xc0 = xn0; xc1 = xn1; xc2 = xn2; xc3 = xn3;
  }

  __syncthreads();   // everyone done READING the attn tile

  // write wave partials: lds[w][8 rows][32 float4 cols]
  {
    float4* pat = (float4*)lds + (size_t)w * 256;
#pragma unroll
    for (int j = 0; j < 4; ++j)
      pat[(qh * 4 + j) * 32 + col] = acc[j];
  }
  __syncthreads();

  // reduce 8 partials and store: 256 float4 outputs
  if (tid < 256) {
    int row = tid >> 5;            // 0..7
    int c   = tid & 31;            // 0..31
    const float4* p = (const float4*)lds + tid;  // == row*32 + c
    float4 r = p[0];
#pragma unroll
    for (int i = 1; i < 8; ++i) {
      float4 t = p[(size_t)i * 256];
      r.x += t.x; r.y += t.y; r.z += t.z; r.w += t.w;
    }
    *(float4*)(out + (size_t)(q0 + row) * D + dt * 128 + c * 4) = r;
  }
}

extern "C" void kernel_launch(void* const* d_in, const int* in_sizes, int n_in,
                              void* d_out, int out_size, void* d_ws, size_t ws_size,
                              hipStream_t stream) {
  const float* inputs  = (const float*)d_in[0];  // [B,TV,D]
  const float* context = (const float*)d_in[1];  // [B,TQ,D]
  const int*   mask    = (const int*)d_in[2];    // [B,TV]
  const float* Wk      = (const float*)d_in[3];  // [D,A]
  const float* bk      = (const float*)d_in[4];  // [A]
  const float* Wq      = (const float*)d_in[5];  // [D,A]
  const float* bq      = (const float*)d_in[6];  // [A]
  const float* attn_v  = (const float*)d_in[7];  // [A]
  float* out = (float*)d_out;                    // [B,TQ,D]

  // Workspace layout (fp32): Eq | EkT | attn  = 0.5MB + 2MB + 4MB
  float* Eq   = (float*)d_ws;             // [B*TQ, A]
  float* EkT  = Eq + B * TQ * A;          // [B, A, TV]  (transposed!)
  float* attn = EkT + (size_t)B * A * TV; // [B*TQ, TV]

  proj_exp_kernel<<<QBLK + KBLK, 512, 0, stream>>>(context, inputs, Wq, bq,
                                                   Wk, bk, Eq, EkT);
  score_softmax_kernel<<<B * TQ / 2, 256, 0, stream>>>(Eq, EkT, attn_v, mask,
                                                       attn);
  pv_kernel<<<dim3(4, 128), 512, 0, stream>>>(attn, inputs, out);
}

// Round 8
// 138.888 us; speedup vs baseline: 1.2924x; 1.2924x over previous
//
#include <hip/hip_runtime.h>
#include <math.h>

// Problem sizes (fixed by the reference)
#define B   4
#define TQ  256
#define TV  1024
#define D   512
#define A   128

#define LOG2E     1.4426950408889634f
#define TWO_LOG2E 2.8853900817779268f
#define NEG_BIG_F (-1e9f)

#define QBLK (B * TQ / 8)   // 128 q-projection blocks
#define KBLK (B * TV / 8)   // 512 k-projection blocks

// ---------------------------------------------------------------------------
// Fused projection + exp(2x) for BOTH q and k.
//   q path: Eq[r, a]     = exp(2*(ctx[r,:]@Wq[:,a] + bq[a]))   [row-major]
//   k path: EkT[b, a, v] = exp(2*(inp[r,:]@Wk[:,a] + bk[a]))   [TRANSPOSED]
// Block = 256 thr (4 waves), 8 rows staged in LDS. Thread owns an a-QUAD
// (float4 of W) x 8 rows = 32 acc; d split 8-way (h = tid>>5, 64 d each).
// Per 4-d unit: 8 ds_read_b128 (96 cyc LDS pipe) feed 128 FMA (256 cyc SIMD)
// -> FMA-bound, unlike round 6 (96 cyc LDS per 64 cyc FMA).
// h-pairs within a wave reduced via shfl; 4 wave-groups via 16 KB LDS.
// ---------------------------------------------------------------------------
__global__ __launch_bounds__(256, 4) void proj_exp_kernel(
    const float* __restrict__ ctx, const float* __restrict__ inp,
    const float* __restrict__ Wq, const float* __restrict__ bq,
    const float* __restrict__ Wk, const float* __restrict__ bk,
    float* __restrict__ Eq, float* __restrict__ EkT) {
  __shared__ float xs[8][D];        // 16 KB
  __shared__ float ps[8][4][A];     // 16 KB (row j, wave-group, a)
  __shared__ float es[A][9];        // 4.6 KB (transpose staging, +1 pad)

  bool isQ = blockIdx.x < QBLK;
  const float* X; const float* W; const float* bias; int r0;
  if (isQ) { X = ctx; W = Wq; bias = bq; r0 = blockIdx.x * 8; }
  else     { X = inp; W = Wk; bias = bk; r0 = (blockIdx.x - QBLK) * 8; }

  int tid = threadIdx.x;

  // stage 8 rows of X (float4, coalesced)
  {
    const float4* Xv = (const float4*)(X + (size_t)r0 * D);
    float4* xsv = (float4*)&xs[0][0];
    for (int i = tid; i < 8 * D / 4; i += 256) xsv[i] = Xv[i];
  }
  __syncthreads();

  int aq = (tid & 31) * 4;      // a-quad base (lanes 0..31 cover a=0..127)
  int h  = tid >> 5;            // 0..7 -> d range [h*64, h*64+64)
  float4 acc[8];
#pragma unroll
  for (int j = 0; j < 8; ++j) acc[j] = make_float4(0.f, 0.f, 0.f, 0.f);

  int dbase = h * 64;
#pragma unroll 2
  for (int dd = 0; dd < 64; dd += 4) {
    int d = dbase + dd;
    float4 w0 = *(const float4*)(W + (size_t)(d + 0) * A + aq);
    float4 w1 = *(const float4*)(W + (size_t)(d + 1) * A + aq);
    float4 w2 = *(const float4*)(W + (size_t)(d + 2) * A + aq);
    float4 w3 = *(const float4*)(W + (size_t)(d + 3) * A + aq);
#pragma unroll
    for (int j = 0; j < 8; ++j) {
      float4 x = *(const float4*)&xs[j][d];  // 2-addr broadcast (free)
      acc[j].x = fmaf(x.x, w0.x, acc[j].x);
      acc[j].y = fmaf(x.x, w0.y, acc[j].y);
      acc[j].z = fmaf(x.x, w0.z, acc[j].z);
      acc[j].w = fmaf(x.x, w0.w, acc[j].w);
      acc[j].x = fmaf(x.y, w1.x, acc[j].x);
      acc[j].y = fmaf(x.y, w1.y, acc[j].y);
      acc[j].z = fmaf(x.y, w1.z, acc[j].z);
      acc[j].w = fmaf(x.y, w1.w, acc[j].w);
      acc[j].x = fmaf(x.z, w2.x, acc[j].x);
      acc[j].y = fmaf(x.z, w2.y, acc[j].y);
      acc[j].z = fmaf(x.z, w2.z, acc[j].z);
      acc[j].w = fmaf(x.z, w2.w, acc[j].w);
      acc[j].x = fmaf(x.w, w3.x, acc[j].x);
      acc[j].y = fmaf(x.w, w3.y, acc[j].y);
      acc[j].z = fmaf(x.w, w3.z, acc[j].z);
      acc[j].w = fmaf(x.w, w3.w, acc[j].w);
    }
  }

  // reduce the two h's within each wave (lane L += lane L+32)
#pragma unroll
  for (int j = 0; j < 8; ++j) {
    acc[j].x += __shfl_down(acc[j].x, 32, 64);
    acc[j].y += __shfl_down(acc[j].y, 32, 64);
    acc[j].z += __shfl_down(acc[j].z, 32, 64);
    acc[j].w += __shfl_down(acc[j].w, 32, 64);
  }
  int g = tid >> 6;             // wave-group 0..3
  if ((tid & 63) < 32) {
#pragma unroll
    for (int j = 0; j < 8; ++j)
      *(float4*)&ps[j][g][aq] = acc[j];
  }
  __syncthreads();

  // finalize: thread -> (row j, a-quad a4); sum 4 wave-groups + bias + exp
  int j  = tid >> 5;            // 0..7
  int a4 = (tid & 31) * 4;
  float4 p0 = *(const float4*)&ps[j][0][a4];
  float4 p1 = *(const float4*)&ps[j][1][a4];
  float4 p2 = *(const float4*)&ps[j][2][a4];
  float4 p3 = *(const float4*)&ps[j][3][a4];
  float4 bz = *(const float4*)(bias + a4);
  float4 ev;
  ev.x = __builtin_amdgcn_exp2f((((p0.x + p1.x) + (p2.x + p3.x)) + bz.x) * TWO_LOG2E);
  ev.y = __builtin_amdgcn_exp2f((((p0.y + p1.y) + (p2.y + p3.y)) + bz.y) * TWO_LOG2E);
  ev.z = __builtin_amdgcn_exp2f((((p0.z + p1.z) + (p2.z + p3.z)) + bz.z) * TWO_LOG2E);
  ev.w = __builtin_amdgcn_exp2f((((p0.w + p1.w) + (p2.w + p3.w)) + bz.w) * TWO_LOG2E);

  if (isQ) {
    *(float4*)(Eq + (size_t)(r0 + j) * A + a4) = ev;   // coalesced per row
  } else {
    es[a4 + 0][j] = ev.x;
    es[a4 + 1][j] = ev.y;
    es[a4 + 2][j] = ev.z;
    es[a4 + 3][j] = ev.w;
    __syncthreads();
    int b  = r0 >> 10;          // TV == 1024
    int v0 = r0 & (TV - 1);
    for (int i = tid; i < A * 8; i += 256) {
      int aa = i >> 3, jj = i & 7;
      EkT[((size_t)b * A + aa) * TV + v0 + jj] = es[aa][jj];
    }
  }
}

// ---------------------------------------------------------------------------
// Scores + softmax: TWO q rows per block, 256 threads (4 waves), 512 blocks
// -> 2 blocks/CU, 8 waves/CU. Thread owns 4 consecutive v for both rows
// (8 independent rcp chains per EkT float4 load). Prefetch distance 2 covers
// the ~250-cyc L2 latency.
//   score[v] = sumV - 2 * sum_a v_a / (Eq[a]*EkT[a,v] + 1)
// ---------------------------------------------------------------------------
__global__ __launch_bounds__(256, 4) void score_softmax_kernel(
    const float* __restrict__ Eq, const float* __restrict__ EkT,
    const float* __restrict__ attn_v, const int* __restrict__ mask,
    float* __restrict__ attn) {
  __shared__ float redA[4], redB[4];
  __shared__ float bc[4];

  int tid = threadIdx.x;
  int v0  = (tid & 63) * 4 + (tid >> 6) * 256;  // wave-contiguous float4
  int r0  = blockIdx.x * 2;
  int b   = r0 >> 8;               // TQ == 256

  const float* eqA = Eq + (size_t)r0 * A;
  const float* eqB = eqA + A;

  float sumV = 0.f;
#pragma unroll 16
  for (int i = 0; i < A; ++i) sumV += attn_v[i];

  const float* ekb = EkT + (size_t)b * A * TV + v0;
  float4 tA = make_float4(0.f, 0.f, 0.f, 0.f);
  float4 tB = make_float4(0.f, 0.f, 0.f, 0.f);

  float4 e0 = *(const float4*)(ekb);
  float4 e1 = *(const float4*)(ekb + (size_t)TV);
#pragma unroll 4
  for (int i = 0; i < A; ++i) {
    float4 en;
    if (i < A - 2) en = *(const float4*)(ekb + (size_t)(i + 2) * TV);
    float av = attn_v[i];
    float qa = eqA[i];
    float qb = eqB[i];
    tA.x = fmaf(av, __builtin_amdgcn_rcpf(fmaf(e0.x, qa, 1.f)), tA.x);
    tA.y = fmaf(av, __builtin_amdgcn_rcpf(fmaf(e0.y, qa, 1.f)), tA.y);
    tA.z = fmaf(av, __builtin_amdgcn_rcpf(fmaf(e0.z, qa, 1.f)), tA.z);
    tA.w = fmaf(av, __builtin_amdgcn_rcpf(fmaf(e0.w, qa, 1.f)), tA.w);
    tB.x = fmaf(av, __builtin_amdgcn_rcpf(fmaf(e0.x, qb, 1.f)), tB.x);
    tB.y = fmaf(av, __builtin_amdgcn_rcpf(fmaf(e0.y, qb, 1.f)), tB.y);
    tB.z = fmaf(av, __builtin_amdgcn_rcpf(fmaf(e0.z, qb, 1.f)), tB.z);
    tB.w = fmaf(av, __builtin_amdgcn_rcpf(fmaf(e0.w, qb, 1.f)), tB.w);
    e0 = e1;
    e1 = en;
  }

  int4 mk = *(const int4*)(mask + b * TV + v0);
  float4 sA, sB;
  sA.x = sumV - 2.f * tA.x + (1.f - (float)mk.x) * NEG_BIG_F;
  sA.y = sumV - 2.f * tA.y + (1.f - (float)mk.y) * NEG_BIG_F;
  sA.z = sumV - 2.f * tA.z + (1.f - (float)mk.z) * NEG_BIG_F;
  sA.w = sumV - 2.f * tA.w + (1.f - (float)mk.w) * NEG_BIG_F;
  sB.x = sumV - 2.f * tB.x + (1.f - (float)mk.x) * NEG_BIG_F;
  sB.y = sumV - 2.f * tB.y + (1.f - (float)mk.y) * NEG_BIG_F;
  sB.z = sumV - 2.f * tB.z + (1.f - (float)mk.z) * NEG_BIG_F;
  sB.w = sumV - 2.f * tB.w + (1.f - (float)mk.w) * NEG_BIG_F;

  float mA = fmaxf(fmaxf(sA.x, sA.y), fmaxf(sA.z, sA.w));
  float mB = fmaxf(fmaxf(sB.x, sB.y), fmaxf(sB.z, sB.w));
  for (int off = 32; off > 0; off >>= 1) {
    mA = fmaxf(mA, __shfl_down(mA, off, 64));
    mB = fmaxf(mB, __shfl_down(mB, off, 64));
  }
  int w = tid >> 6;
  if ((tid & 63) == 0) { redA[w] = mA; redB[w] = mB; }
  __syncthreads();
  if (tid == 0) {
    bc[0] = fmaxf(fmaxf(redA[0], redA[1]), fmaxf(redA[2], redA[3]));
    bc[1] = fmaxf(fmaxf(redB[0], redB[1]), fmaxf(redB[2], redB[3]));
  }
  __syncthreads();
  float MA = bc[0], MB = bc[1];

  float4 eAv, eBv;
  eAv.x = __builtin_amdgcn_exp2f((sA.x - MA) * LOG2E);
  eAv.y = __builtin_amdgcn_exp2f((sA.y - MA) * LOG2E);
  eAv.z = __builtin_amdgcn_exp2f((sA.z - MA) * LOG2E);
  eAv.w = __builtin_amdgcn_exp2f((sA.w - MA) * LOG2E);
  eBv.x = __builtin_amdgcn_exp2f((sB.x - MB) * LOG2E);
  eBv.y = __builtin_amdgcn_exp2f((sB.y - MB) * LOG2E);
  eBv.z = __builtin_amdgcn_exp2f((sB.z - MB) * LOG2E);
  eBv.w = __builtin_amdgcn_exp2f((sB.w - MB) * LOG2E);
  float lA = (eAv.x + eAv.y) + (eAv.z + eAv.w);
  float lB = (eBv.x + eBv.y) + (eBv.z + eBv.w);
  for (int off = 32; off > 0; off >>= 1) {
    lA += __shfl_down(lA, off, 64);
    lB += __shfl_down(lB, off, 64);
  }
  __syncthreads();   // protect red[] before rewrite
  if ((tid & 63) == 0) { redA[w] = lA; redB[w] = lB; }
  __syncthreads();
  if (tid == 0) {
    bc[2] = (redA[0] + redA[1]) + (redA[2] + redA[3]);
    bc[3] = (redB[0] + redB[1]) + (redB[2] + redB[3]);
  }
  __syncthreads();
  float iA = 1.f / bc[2];
  float iB = 1.f / bc[3];

  float4 oA = make_float4(eAv.x * iA, eAv.y * iA, eAv.z * iA, eAv.w * iA);
  float4 oB = make_float4(eBv.x * iB, eBv.y * iB, eBv.z * iB, eBv.w * iB);
  *(float4*)(attn + (size_t)r0 * TV + v0)       = oA;
  *(float4*)(attn + (size_t)(r0 + 1) * TV + v0) = oB;
}

// ---------------------------------------------------------------------------
// out[b,q,:] = sum_v attn[b,q,v] * inputs[b,v,:]   -- NO ATOMICS.
// Block tile: 8 q x 128 d over the FULL v range; v-sum split across the 8
// waves (disjoint 128-v chunks, no duplicated X traffic), wave partials
// reduced through LDS (reusing the 32 KB attn-tile buffer), plain coalesced
// store. grid (dt=4, qtile=128) = 512 blocks x 512 thr -> 2 blocks/CU,
// 16 waves/CU. Register tile 4q x 4d = 16 acc; 16 FMA per X float4 load.
// ---------------------------------------------------------------------------
__global__ __launch_bounds__(512, 4) void pv_kernel(
    const float* __restrict__ attn, const float* __restrict__ X,
    float* __restrict__ out) {
  __shared__ float lds[8 * 1024];    // 32 KB: attn tile, then 8 partial tiles
  int dt = blockIdx.x;               // 0..3, d-slice of 128
  int q0 = blockIdx.y * 8;           // global row (b*TQ + q), 128 tiles
  int b  = q0 >> 8;                  // TQ == 256
  int tid  = threadIdx.x;
  int w    = tid >> 6;               // wave 0..7 -> v range [w*128, w*128+128)
  int lane = tid & 63;
  int col  = lane & 31;              // float4 d-column
  int qh   = lane >> 5;              // 0..1 -> q rows qh*4 .. qh*4+3
  int d0 = dt * 128 + col * 4;

  // stage attn tile: 8 rows x 1024 v (float4, coalesced)
  {
    const float4* src = (const float4*)(attn + (size_t)q0 * TV);
    float4* dst = (float4*)lds;
    for (int i = tid; i < 8 * 256; i += 512) dst[i] = src[i];
  }
  __syncthreads();

  float4 acc[4];
#pragma unroll
  for (int j = 0; j < 4; ++j) acc[j] = make_float4(0.f, 0.f, 0.f, 0.f);

  int vbase = w * 128;
  const float* Xb = X + ((size_t)b * TV + vbase) * D + d0;
  const float* arow = &lds[(qh * 4) * 1024 + vbase];  // 4 rows, stride 1024

  float4 xc0 = *(const float4*)(Xb + (size_t)0 * D);
  float4 xc1 = *(const float4*)(Xb + (size_t)1 * D);
  float4 xc2 = *(const float4*)(Xb + (size_t)2 * D);
  float4 xc3 = *(const float4*)(Xb + (size_t)3 * D);

  for (int vi = 0; vi < 128; vi += 4) {
    float4 xn0, xn1, xn2, xn3;
    if (vi < 124) {
      const float* Xn = Xb + (size_t)(vi + 4) * D;
      xn0 = *(const float4*)(Xn + (size_t)0 * D);
      xn1 = *(const float4*)(Xn + (size_t)1 * D);
      xn2 = *(const float4*)(Xn + (size_t)2 * D);
      xn3 = *(const float4*)(Xn + (size_t)3 * D);
    }
#pragma unroll
    for (int j = 0; j < 4; ++j) {
      float4 av = *(const float4*)(arow + j * 1024 + vi);  // 2-addr bcast
      acc[j].x = fmaf(av.x, xc0.x, acc[j].x);
      acc[j].y = fmaf(av.x, xc0.y, acc[j].y);
      acc[j].z = fmaf(av.x, xc0.z, acc[j].z);
      acc[j].w = fmaf(av.x, xc0.w, acc[j].w);
      acc[j].x = fmaf(av.y, xc1.x, acc[j].x);
      acc[j].y = fmaf(av.y, xc1.y, acc[j].y);
      acc[j].z = fmaf(av.y, xc1.z, acc[j].z);
      acc[j].w = fmaf(av.y, xc1.w, acc[j].w);
      acc[j].x = fmaf(av.z, xc2.x, acc[j].x);
      acc[j].y = fmaf(av.z, xc2.y, acc[j].y);
      acc[j].z = fmaf(av.z, xc2.z, acc[j].z);
      acc[j].w = fmaf(av.z, xc2.w, acc[j].w);
      acc[j].x = fmaf(av.w, xc3.x, acc[j].x);
      acc[j].y = fmaf(av.w, xc3.y, acc[j].y);
      acc[j].z = fmaf(av.w, xc3.z, acc[j].z);
      acc[j].w = fmaf(av.w, xc3.w, acc[j].w);
    }
    xc0 = xn0; xc1 = xn1; xc2 = xn2; xc3 = xn3;
  }

  __syncthreads();   // everyone done READING the attn tile

  // write wave partials: lds[w][8 rows][32 float4 cols]
  {
    float4* pat = (float4*)lds + (size_t)w * 256;
#pragma unroll
    for (int j = 0; j < 4; ++j)
      pat[(qh * 4 + j) * 32 + col] = acc[j];
  }
  __syncthreads();

  // reduce 8 partials and store: 256 float4 outputs
  if (tid < 256) {
    int row = tid >> 5;            // 0..7
    int c   = tid & 31;            // 0..31
    const float4* p = (const float4*)lds + tid;  // == row*32 + c
    float4 r = p[0];
#pragma unroll
    for (int i = 1; i < 8; ++i) {
      float4 t = p[(size_t)i * 256];
      r.x += t.x; r.y += t.y; r.z += t.z; r.w += t.w;
    }
    *(float4*)(out + (size_t)(q0 + row) * D + dt * 128 + c * 4) = r;
  }
}

extern "C" void kernel_launch(void* const* d_in, const int* in_sizes, int n_in,
                              void* d_out, int out_size, void* d_ws, size_t ws_size,
                              hipStream_t stream) {
  const float* inputs  = (const float*)d_in[0];  // [B,TV,D]
  const float* context = (const float*)d_in[1];  // [B,TQ,D]
  const int*   mask    = (const int*)d_in[2];    // [B,TV]
  const float* Wk      = (const float*)d_in[3];  // [D,A]
  const float* bk      = (const float*)d_in[4];  // [A]
  const float* Wq      = (const float*)d_in[5];  // [D,A]
  const float* bq      = (const float*)d_in[6];  // [A]
  const float* attn_v  = (const float*)d_in[7];  // [A]
  float* out = (float*)d_out;                    // [B,TQ,D]

  // Workspace layout (fp32): Eq | EkT | attn  = 0.5MB + 2MB + 4MB
  float* Eq   = (float*)d_ws;             // [B*TQ, A]
  float* EkT  = Eq + B * TQ * A;          // [B, A, TV]  (transposed!)
  float* attn = EkT + (size_t)B * A * TV; // [B*TQ, TV]

  proj_exp_kernel<<<QBLK + KBLK, 256, 0, stream>>>(context, inputs, Wq, bq,
                                                   Wk, bk, Eq, EkT);
  score_softmax_kernel<<<B * TQ / 2, 256, 0, stream>>>(Eq, EkT, attn_v, mask,
                                                       attn);
  pv_kernel<<<dim3(4, 128), 512, 0, stream>>>(attn, inputs, out);
}